// Round 6
// baseline (185.661 us; speedup 1.0000x reference)
//
#include <hip/hip_runtime.h>

#define NODE 2048
#define KDIM 2048
#define CLUSTER 32
#define IN_DIM 64
#define OUT_DIM 64
#define BATCH 32

typedef short short8 __attribute__((ext_vector_type(8)));
typedef short short4v __attribute__((ext_vector_type(4)));
typedef float f32x4 __attribute__((ext_vector_type(4)));

__device__ __forceinline__ short f2bf(float f) {
  unsigned u = __float_as_uint(f);
  u += 0x7fffu + ((u >> 16) & 1u);   // round-to-nearest-even
  return (short)(u >> 16);
}
__device__ __forceinline__ float bf2f(short s) {
  return __uint_as_float(((unsigned)(unsigned short)s) << 16);
}

typedef __attribute__((address_space(1))) const unsigned int gu32;
typedef __attribute__((address_space(3))) unsigned int lu32;
__device__ __forceinline__ void gl16(const void* g, void* l) {
  __builtin_amdgcn_global_load_lds((gu32*)g, (lu32*)l, 16, 0, 0);
}

// ---------------------------------------------------------------------------
// k1: w = alpha @ beta, stored as bf16 in MFMA-B fragment layout (unchanged)
// ---------------------------------------------------------------------------
__global__ __launch_bounds__(256) void k1_wgen(
    const float* __restrict__ alpha, const float* __restrict__ beta,
    short8* __restrict__ w_frag) {
  const int bid = blockIdx.x;
  const int ngrp = bid >> 1;
  const int ihalf = bid & 1;
  const int t = threadIdx.x;
  const int o = t & 63;
  const int igl = t >> 6;
  const int i0 = ihalf * 32 + igl * 8;
  const int n0 = ngrp * 8;

  float acc[8][8];
#pragma unroll
  for (int r = 0; r < 8; ++r)
#pragma unroll
    for (int j = 0; j < 8; ++j) acc[r][j] = 0.f;

  for (int k = 0; k < CLUSTER; ++k) {
    float av[8];
#pragma unroll
    for (int r = 0; r < 8; ++r) av[r] = alpha[(n0 + r) * CLUSTER + k];
    const float* bp = beta + k * (IN_DIM * OUT_DIM) + i0 * OUT_DIM + o;
#pragma unroll
    for (int j = 0; j < 8; ++j) {
      float bv = bp[j * OUT_DIM];
#pragma unroll
      for (int r = 0; r < 8; ++r) acc[r][j] += av[r] * bv;
    }
  }
#pragma unroll
  for (int r = 0; r < 8; ++r) {
    short8 s;
#pragma unroll
    for (int j = 0; j < 8; ++j) s[j] = f2bf(acc[r][j]);
    w_frag[((n0 + r) * 8 + (i0 >> 3)) * 64 + o] = s;
  }
}

// ---------------------------------------------------------------------------
// k2: h2[b,n,o] = sum_i h[b,n,i]*w[n,i,o] + bias[o]  (unchanged)
// ---------------------------------------------------------------------------
__global__ __launch_bounds__(64) void k2_h2(
    const float* __restrict__ h, const short8* __restrict__ w_frag,
    const float* __restrict__ bias, short* __restrict__ h2_frag) {
  const int n = blockIdx.x;
  const int l = threadIdx.x;
  const int lr = l & 15, lk = l >> 4;

  short8 afr[2][2];
#pragma unroll
  for (int m = 0; m < 2; ++m)
#pragma unroll
    for (int kf = 0; kf < 2; ++kf) {
      const float* hp =
          h + ((size_t)(m * 16 + lr) * NODE + n) * IN_DIM + kf * 32 + lk * 8;
      f32x4 v0 = *(const f32x4*)hp;
      f32x4 v1 = *(const f32x4*)(hp + 4);
      short8 s;
#pragma unroll
      for (int j = 0; j < 4; ++j) { s[j] = f2bf(v0[j]); s[j + 4] = f2bf(v1[j]); }
      afr[m][kf] = s;
    }

  short8 bfr[4][2];
#pragma unroll
  for (int ng = 0; ng < 4; ++ng)
#pragma unroll
    for (int kf = 0; kf < 2; ++kf)
      bfr[ng][kf] = w_frag[(n * 8 + kf * 4 + lk) * 64 + ng * 16 + lr];

  f32x4 acc[2][4];
#pragma unroll
  for (int m = 0; m < 2; ++m)
#pragma unroll
    for (int ng = 0; ng < 4; ++ng) acc[m][ng] = (f32x4){0.f, 0.f, 0.f, 0.f};

#pragma unroll
  for (int kf = 0; kf < 2; ++kf)
#pragma unroll
    for (int m = 0; m < 2; ++m)
#pragma unroll
      for (int ng = 0; ng < 4; ++ng)
        acc[m][ng] = __builtin_amdgcn_mfma_f32_16x16x32_bf16(
            afr[m][kf], bfr[ng][kf], acc[m][ng], 0, 0, 0);

#pragma unroll
  for (int m = 0; m < 2; ++m)
#pragma unroll
    for (int ng = 0; ng < 4; ++ng) {
      const int o = ng * 16 + lr;
      const float bv = bias[o];
#pragma unroll
      for (int r = 0; r < 4; ++r) {
        const int b = m * 16 + lk * 4 + r;
        h2_frag[(((size_t)b * 256 + (n >> 3)) * 64 + o) * 8 + (n & 7)] =
            f2bf(acc[m][ng][r] + bv);
      }
    }
}

// ---------------------------------------------------------------------------
// k3 (hot): out[b] = a[b] @ h2[b] + h2[b]
// ADDRESS-CONTIGUOUS A-READ (fillBuffer-style streams):
//  block = (batch, 128-row tile); 8 groups of 16 rows. Each group's A data
//  (16 consecutive 8 KiB rows = 128 KiB) is staged in PURE ADDRESS ORDER via
//  global_load_lds (1 KiB contiguous per instr; 32 KiB contiguous per wave)
//  into LDS f32 tile [16][2052] (16 B row pad). Compute: k-split across the
//  4 waves (wave w: k in [512w,512w+512)), 16x64 partials reduced via LDS
//  scratch; residual fused in reduce. B-frags stream from L2 (XCD swizzle
//  keeps 4 batches' panels = 1 MiB per XCD L2).
// ---------------------------------------------------------------------------
__global__ __launch_bounds__(256) void k3_main(
    const float* __restrict__ a, const short* __restrict__ h2f,
    float* __restrict__ out) {
  __shared__ float tileF[16][2052];        // 131328 B (8208 B per row)
  __shared__ float scratch[4][16][64];     // 16384 B
  const int bid0 = blockIdx.x;                    // 512
  const int swz = (bid0 & 7) * 64 + (bid0 >> 3);  // XCD-cluster same-batch
  const int b = swz >> 4;                         // 32 batches
  const int rt = swz & 15;                        // 16 row tiles of 128
  const int t = threadIdx.x;
  const int wid = t >> 6;                         // 0..3
  const int l = t & 63;
  const int lr = l & 15, lk = l >> 4;

  const char* aBatch = (const char*)(a + (size_t)b * NODE * KDIM);
  const short8* bwave =
      (const short8*)h2f + ((size_t)b * 256 + lk) * 64 + lr + (size_t)(wid * 16) * 256;

#pragma unroll 1
  for (int g = 0; g < 8; ++g) {
    const int rg0 = rt * 128 + g * 16;

    // ---- stage: 128 KiB contiguous; wave wid = contiguous 32 KiB ----
    {
      const char* gbase = aBatch + (size_t)rg0 * (KDIM * 4) + (size_t)l * 16;
      char* lbase = (char*)&tileF[0][0];
#pragma unroll
      for (int j = 0; j < 32; ++j) {
        const int i = wid * 32 + j;               // instr id 0..127
        gl16(gbase + (size_t)i * 1024,
             lbase + (i >> 3) * 8208 + (i & 7) * 1024);
      }
    }
    __syncthreads();                              // drains vmcnt, tile visible

    // ---- compute: wave wid owns ksteps wid*16 .. wid*16+15 (k-split) ----
    f32x4 acc[4];
#pragma unroll
    for (int ng = 0; ng < 4; ++ng) acc[ng] = (f32x4){0.f, 0.f, 0.f, 0.f};

    short8 Bbuf[3][4];
#define LB(ks, BR)                                        \
    do {                                                  \
      const short8* q_ = bwave + (ks) * 256;              \
      BR[0] = q_[0];  BR[1] = q_[16];                     \
      BR[2] = q_[32]; BR[3] = q_[48];                     \
    } while (0)
    LB(0, Bbuf[0]); LB(1, Bbuf[1]); LB(2, Bbuf[2]);

#pragma unroll
    for (int ks = 0; ks < 16; ++ks) {
      const float* ap = &tileF[lr][wid * 512 + ks * 32 + lk * 8];
      f32x4 lo = *(const f32x4*)ap;
      f32x4 hi = *(const f32x4*)(ap + 4);
      short8 af;
#pragma unroll
      for (int j = 0; j < 4; ++j) { af[j] = f2bf(lo[j]); af[j + 4] = f2bf(hi[j]); }
#pragma unroll
      for (int ng = 0; ng < 4; ++ng)
        acc[ng] = __builtin_amdgcn_mfma_f32_16x16x32_bf16(
            af, Bbuf[ks % 3][ng], acc[ng], 0, 0, 0);
      if (ks + 3 < 16) LB(ks + 3, Bbuf[ks % 3]);
    }
#undef LB

    // ---- reduce partials via LDS scratch, fuse residual, store ----
#pragma unroll
    for (int ng = 0; ng < 4; ++ng)
#pragma unroll
      for (int rr = 0; rr < 4; ++rr)
        scratch[wid][lk * 4 + rr][ng * 16 + lr] = acc[ng][rr];
    __syncthreads();

    {
      const int r16 = t >> 4;
      const int c0 = (t & 15) * 4;
      f32x4 s = *(const f32x4*)&scratch[0][r16][c0];
      s += *(const f32x4*)&scratch[1][r16][c0];
      s += *(const f32x4*)&scratch[2][r16][c0];
      s += *(const f32x4*)&scratch[3][r16][c0];
      const int row = rg0 + r16;
      const size_t rbase = ((size_t)b * 256 + (row >> 3)) * 64;
      f32x4 o4;
#pragma unroll
      for (int cc = 0; cc < 4; ++cc)
        o4[cc] = s[cc] + bf2f(h2f[(rbase + c0 + cc) * 8 + (row & 7)]);
      *(f32x4*)&out[((size_t)b * NODE + row) * 64 + c0] = o4;
    }
    // next stage(g+1) overwrites tileF only after compute(g) finished reading
    // it (pre-scratch barrier); epilogue touches scratch/global only.
  }
}

extern "C" void kernel_launch(void* const* d_in, const int* in_sizes, int n_in,
                              void* d_out, int out_size, void* d_ws, size_t ws_size,
                              hipStream_t stream) {
  const float* a     = (const float*)d_in[0];
  const float* h     = (const float*)d_in[1];
  const float* alpha = (const float*)d_in[2];
  const float* beta  = (const float*)d_in[3];
  const float* bias  = (const float*)d_in[4];
  float* out = (float*)d_out;

  short8* w_frag = (short8*)d_ws;
  short*  h2_frag = (short*)((char*)d_ws + (size_t)(16u << 20));

  k1_wgen<<<dim3(512), dim3(256), 0, stream>>>(alpha, beta, w_frag);
  k2_h2 <<<dim3(NODE), dim3(64),  0, stream>>>(h, w_frag, bias, h2_frag);
  k3_main<<<dim3(512), dim3(256), 0, stream>>>(a, h2_frag, out);
}